// Round 18
// baseline (58.003 us; speedup 1.0000x reference)
//
#include <hip/hip_runtime.h>
#include <math.h>

#define WIN 16       // hard cap: adaptive window within +/-16 (R13/R17-verified)
#define THRESH 20.0f // keep indices with score >= m - THRESH (e^-20 truncation)
#define FPW 8        // frames per wave
#define NW  4        // waves per block (fully independent)
#define FPB (FPW * NW)

// Kernel 1: per-batch inclusive cumsum of durations (double precision scan),
// centers c[b,n] = cumsum(dur)[b,n] - 0.5*dur[b,n]   (verbatim)
__global__ void centers_kernel(const float* __restrict__ dur,
                               float* __restrict__ c, int N) {
    extern __shared__ double s[];
    int b = blockIdx.x;
    int n = threadIdx.x;
    float d = (n < N) ? dur[(size_t)b * N + n] : 0.0f;
    if (n < N) s[n] = (double)d;
    __syncthreads();
    for (int off = 1; off < N; off <<= 1) {
        double v = (n >= off && n < N) ? s[n - off] : 0.0;
        __syncthreads();
        if (n < N) s[n] += v;
        __syncthreads();
    }
    if (n < N) c[(size_t)b * N + n] = (float)(s[n] - 0.5 * (double)d);
}

// Kernel 1.5: nearest index + adaptive window + m + 1/sum (verbatim R17,
// verified at absmax 0.015625). pack = a | (K<<16).
__global__ __launch_bounds__(256) void bounds_kernel(
    const float* __restrict__ c, const int* __restrict__ lens,
    int* __restrict__ pack, float* __restrict__ marr,
    float* __restrict__ inv, int N, int T) {
    int gt = blockIdx.x * 256 + threadIdx.x;   // over B*T
    int b = gt / T;
    int t = gt - b * T;
    const float* cb = c + (size_t)b * N;
    int L = lens[b];
    if (L < 1) L = 1;
    if (L > N) L = N;
    float tf = (float)t;
    int lo = 0, hi = L;
    while (lo < hi) {
        int mid = (lo + hi) >> 1;
        if (cb[mid] < tf) lo = mid + 1; else hi = mid;
    }
    int j = lo;
    if (j >= L) j = L - 1;
    float cj   = cb[j];
    float cjm1 = cb[(j > 0) ? (j - 1) : 0];
    if (j > 0 && (tf - cjm1) < (cj - tf)) j--;
    float dm = tf - cb[j];
    float m = -0.5f * dm * dm;                 // max of windowed scores
    float lim = m - THRESH;
    int aCap = j - WIN; if (aCap < 0) aCap = 0;
    int eCap = j + WIN; if (eCap > L - 1) eCap = L - 1;
    int a = j, e = j;
    while (a > aCap) {
        float d = tf - cb[a - 1];
        if (-0.5f * d * d >= lim) --a; else break;
    }
    while (e < eCap) {
        float d = tf - cb[e + 1];
        if (-0.5f * d * d >= lim) ++e; else break;
    }
    float sum = 0.0f;
    for (int k = a; k <= e; ++k) {
        float d  = tf - cb[k];
        float sc = -0.5f * d * d;
        sum += __expf(sc - m);
    }
    pack[gt] = a | ((e - a + 1) << 16);
    marr[gt] = m;
    inv[gt]  = 1.0f / sum;
}

// Kernel 2: fully wave-independent, LDS-free. Each wave: its 8 frames over
// its OWN union window (~half the block union), rows loaded directly from
// L2 with the R11-verified depth-2 rotating pipeline. Weights: verbatim
// R13/R17 per-lane expression + readlane broadcast. Per frame the nonzero
// fma terms are exactly its window in ascending k => bit-identical to R17.
__global__ __launch_bounds__(256, 4) void upsample_direct(
    const float* __restrict__ x,    // [B,N,H]
    const float* __restrict__ c,    // [B,N]
    const int* __restrict__ pack,   // [B,T] a | (K<<16)
    const float* __restrict__ marr, // [B,T] max score
    const float* __restrict__ inv,  // [B,T] softmax 1/sum
    float* __restrict__ out,        // [B,T,H]
    int B, int N, int H, int T) {
    int nwg = gridDim.x;
    int bid = blockIdx.x;
    if ((nwg & 7) == 0) {                  // XCD-bijective swizzle
        int cpx = nwg >> 3;
        bid = (bid & 7) * cpx + (bid >> 3);
    }
    int wave = threadIdx.x >> 6;
    int lane = threadIdx.x & 63;

    int tilesPerB = T / FPB;
    int b   = bid / tilesPerB;
    int t0  = (bid - b * tilesPerB) * FPB + wave * FPW;

    const float* cb = c + (size_t)b * N;

    // ---- per-frame window params (precomputed; wave-uniform loads) ----
    const int*   pb  = pack + (size_t)b * T + t0;
    const float* mb  = marr + (size_t)b * T + t0;
    const float* ivb = inv  + (size_t)b * T + t0;
    float m_[FPW], iv[FPW];
    int a[FPW], K[FPW];
    int amin = 0x7fffffff, emax = 0;
    #pragma unroll
    for (int f = 0; f < FPW; ++f) {
        int pk = pb[f];
        a[f] = pk & 0xffff;
        K[f] = pk >> 16;
        m_[f] = mb[f];
        iv[f] = ivb[f];
        int ef = a[f] + K[f] - 1;
        if (a[f] < amin) amin = a[f];
        if (ef > emax)   emax = ef;
    }
    int span = emax - amin + 1;            // wave union (typ. 3-8)

    const float4* rbase = (const float4*)(x + ((size_t)b * N + amin) * (size_t)H);
    int H4 = H >> 2;                       // 128 float4 per row

    float4 acc[FPW][2];
    #pragma unroll
    for (int f = 0; f < FPW; ++f) {
        acc[f][0] = make_float4(0.f, 0.f, 0.f, 0.f);
        acc[f][1] = make_float4(0.f, 0.f, 0.f, 0.f);
    }

    for (int kb = 0; kb < span; kb += 64) {   // outer chunk (typ. 1 iter)
        int klen = span - kb; if (klen > 64) klen = 64;

        // per-lane weights for union index kb+lane (verbatim R13/R17)
        int nidx = amin + kb + lane;
        int ci = nidx; if (ci > N - 1) ci = N - 1;
        float cv = cb[ci];
        float wv[FPW];
        #pragma unroll
        for (int f = 0; f < FPW; ++f) {
            float d  = (float)(t0 + f) - cv;
            float wval = __expf(-0.5f * d * d - m_[f]) * iv[f];
            unsigned q = (unsigned)(nidx - a[f]);
            wv[f] = (q < (unsigned)K[f]) ? wval : 0.0f;
        }

        // depth-2 rotating load pipeline (verbatim R11 structure)
        const float4* rp = rbase + (size_t)kb * H4;
        float4 va0, vb0, va1, vb1;
        va0 = rp[lane]; vb0 = rp[64 + lane];
        if (klen > 1) { va1 = rp[H4 + lane]; vb1 = rp[H4 + 64 + lane]; }
        for (int k = 0; k < klen; ++k) {
            float4 na, nb;
            if (k + 2 < klen) {
                const float4* rn = rp + (size_t)(k + 2) * H4;
                na = rn[lane]; nb = rn[64 + lane];
            }
            float wk[FPW];
            #pragma unroll
            for (int f = 0; f < FPW; ++f)
                wk[f] = __uint_as_float(
                    __builtin_amdgcn_readlane(__float_as_uint(wv[f]), k));
            #pragma unroll
            for (int f = 0; f < FPW; ++f) {
                acc[f][0].x = fmaf(wk[f], va0.x, acc[f][0].x);
                acc[f][0].y = fmaf(wk[f], va0.y, acc[f][0].y);
                acc[f][0].z = fmaf(wk[f], va0.z, acc[f][0].z);
                acc[f][0].w = fmaf(wk[f], va0.w, acc[f][0].w);
                acc[f][1].x = fmaf(wk[f], vb0.x, acc[f][1].x);
                acc[f][1].y = fmaf(wk[f], vb0.y, acc[f][1].y);
                acc[f][1].z = fmaf(wk[f], vb0.z, acc[f][1].z);
                acc[f][1].w = fmaf(wk[f], vb0.w, acc[f][1].w);
            }
            va0 = va1; vb0 = vb1;
            va1 = na;  vb1 = nb;
        }
    }

    // ---- store the wave's 8 frames (verbatim) ----
    float* obase = out + ((size_t)b * T + t0) * (size_t)H;
    #pragma unroll
    for (int f = 0; f < FPW; ++f) {
        float4* o = (float4*)(obase + (size_t)f * H);
        o[lane]      = acc[f][0];
        o[64 + lane] = acc[f][1];
    }
}

extern "C" void kernel_launch(void* const* d_in, const int* in_sizes, int n_in,
                              void* d_out, int out_size, void* d_ws, size_t ws_size,
                              hipStream_t stream) {
    const float* x    = (const float*)d_in[0];  // [B,N,H] f32
    const int*   lens = (const int*)d_in[1];    // [B] int
    const float* dur  = (const float*)d_in[2];  // [B,N] f32

    int B  = in_sizes[1];
    int BN = in_sizes[2];
    int N  = BN / B;
    int H  = in_sizes[0] / BN;
    int T  = out_size / (B * H);

    size_t cB  = (size_t)B * N * sizeof(float);
    size_t btB = (size_t)B * T * sizeof(int);

    float* c   = (float*)d_ws;
    int*   pk  = (int*)((char*)d_ws + cB);
    float* mar = (float*)((char*)pk + btB);
    float* ivr = (float*)((char*)mar + btB);

    centers_kernel<<<B, N, N * sizeof(double), stream>>>(dur, c, N);
    bounds_kernel<<<(B * T) / 256, 256, 0, stream>>>(c, lens, pk, mar, ivr, N, T);

    int blocks = (B * T) / FPB;             // 32 frames per block
    upsample_direct<<<blocks, 256, 0, stream>>>(x, c, pk, mar, ivr,
                                                (float*)d_out, B, N, H, T);
}

// Round 19
// 35.232 us; speedup vs baseline: 1.6463x; 1.6463x over previous
//
#include <hip/hip_runtime.h>
#include <math.h>

#define WIN 16       // hard cap: adaptive window within +/-16 (R13/R17-verified)
#define THRESH 20.0f // keep indices with score >= m - THRESH (e^-20 truncation)
#define FPW 8        // frames per wave
#define NW  4        // waves per block
#define FPB (FPW * NW)   // 32 frames per block
#define CH  16       // staged rows per chunk (32 KB)

#define AS1 __attribute__((address_space(1)))
#define AS3 __attribute__((address_space(3)))

// Fused prep: one block = (batch b, 256-frame chunk). Redundant per-block
// double-precision Hillis-Steele scan in LDS (identical update order to the
// verified centers_kernel => bit-identical centers), then the verified
// adaptive-bounds code reading centers from LDS (fast binary search).
// Emits pm = {asfloat(a|K<<16), m, inv, 0} per frame; chunk 0 writes c.
__global__ __launch_bounds__(256) void prep_kernel(
    const float* __restrict__ dur, const int* __restrict__ lens,
    float* __restrict__ c, float4* __restrict__ pm, int N, int T) {
    __shared__ double s[512];
    __shared__ float cf[512];
    int tpc = T >> 8;                      // 256-frame chunks per batch
    int b   = blockIdx.x / tpc;
    int tc  = blockIdx.x - b * tpc;
    int tid = threadIdx.x;

    int n0 = tid, n1 = tid + 256;          // two scan elements per thread
    float d0 = dur[(size_t)b * N + n0];
    float d1 = dur[(size_t)b * N + n1];
    s[n0] = (double)d0; s[n1] = (double)d1;
    __syncthreads();
    for (int off = 1; off < N; off <<= 1) {
        double v0 = (n0 >= off) ? s[n0 - off] : 0.0;
        double v1 = (n1 >= off) ? s[n1 - off] : 0.0;
        __syncthreads();
        s[n0] += v0; s[n1] += v1;
        __syncthreads();
    }
    cf[n0] = (float)(s[n0] - 0.5 * (double)d0);
    cf[n1] = (float)(s[n1] - 0.5 * (double)d1);
    __syncthreads();
    if (tc == 0) {                         // write centers once per batch
        c[(size_t)b * N + n0] = cf[n0];
        c[(size_t)b * N + n1] = cf[n1];
    }

    int L = lens[b];
    if (L < 1) L = 1;
    if (L > N) L = N;
    int t = tc * 256 + tid;
    float tf = (float)t;
    int lo = 0, hi = L;
    while (lo < hi) {
        int mid = (lo + hi) >> 1;
        if (cf[mid] < tf) lo = mid + 1; else hi = mid;
    }
    int j = lo;
    if (j >= L) j = L - 1;
    float cj   = cf[j];
    float cjm1 = cf[(j > 0) ? (j - 1) : 0];
    if (j > 0 && (tf - cjm1) < (cj - tf)) j--;
    float dm = tf - cf[j];
    float m = -0.5f * dm * dm;             // max of windowed scores
    float lim = m - THRESH;
    int aCap = j - WIN; if (aCap < 0) aCap = 0;
    int eCap = j + WIN; if (eCap > L - 1) eCap = L - 1;
    int a = j, e = j;
    while (a > aCap) {
        float d = tf - cf[a - 1];
        if (-0.5f * d * d >= lim) --a; else break;
    }
    while (e < eCap) {
        float d = tf - cf[e + 1];
        if (-0.5f * d * d >= lim) ++e; else break;
    }
    float sum = 0.0f;
    for (int k = a; k <= e; ++k) {
        float d = tf - cf[k];
        sum += __expf(-0.5f * d * d - m);
    }
    float4 o;
    o.x = __uint_as_float((unsigned)(a | ((e - a + 1) << 16)));
    o.y = m;
    o.z = 1.0f / sum;
    o.w = 0.0f;
    pm[(size_t)b * T + t] = o;
}

// Main kernel: verbatim R17 (verified 39.9us / absmax 0.015625) except the
// per-frame params come from the packed float4 array (1 load round vs 3).
__global__ __launch_bounds__(256, 4) void upsample_rl(
    const float* __restrict__ x,    // [B,N,H]
    const float* __restrict__ c,    // [B,N]
    const float4* __restrict__ pm,  // [B,T] {asfloat(a|K<<16), m, inv, -}
    float* __restrict__ out,        // [B,T,H]
    int B, int N, int H, int T) {
    __shared__ float rows[CH][512];        // 32 KB staged input rows (H=512)
    __shared__ int   bmin[NW], bmax[NW];   // per-wave window extremes

    int nwg = gridDim.x;
    int bid = blockIdx.x;
    if ((nwg & 7) == 0) {                  // XCD-bijective swizzle
        int cpx = nwg >> 3;
        bid = (bid & 7) * cpx + (bid >> 3);
    }
    int wave = threadIdx.x >> 6;
    int lane = threadIdx.x & 63;

    int tilesPerB = T / FPB;
    int b   = bid / tilesPerB;
    int t0  = (bid - b * tilesPerB) * FPB + wave * FPW;

    const float* cb = c + (size_t)b * N;

    // ---- per-frame window params: one packed float4 per frame ----
    const float4* pmb = pm + (size_t)b * T + t0;
    float tf[FPW], m_[FPW], iv[FPW];
    int a[FPW], K[FPW];
    int amin = 0x7fffffff, emax = 0;
    #pragma unroll
    for (int f = 0; f < FPW; ++f) {
        tf[f] = (float)(t0 + f);
        float4 p = pmb[f];
        unsigned pk = __float_as_uint(p.x);
        a[f] = (int)(pk & 0xffffu);
        K[f] = (int)(pk >> 16);
        m_[f] = p.y;
        iv[f] = p.z;
        int ef = a[f] + K[f] - 1;
        if (a[f] < amin) amin = a[f];
        if (ef > emax)   emax = ef;
    }

    // ---- block union window: explicit min/max across the 4 waves ----
    if (lane == 0) { bmin[wave] = amin; bmax[wave] = emax; }
    __syncthreads();
    int n0 = min(min(bmin[0], bmin[1]), min(bmin[2], bmin[3]));
    int ne = max(max(bmax[0], bmax[1]), max(bmax[2], bmax[3]));
    int span = ne - n0 + 1;

    const float* gbase = x + ((size_t)b * N + n0) * (size_t)H;

    float4 acc[FPW][2];
    #pragma unroll
    for (int f = 0; f < FPW; ++f) {
        acc[f][0] = make_float4(0.f, 0.f, 0.f, 0.f);
        acc[f][1] = make_float4(0.f, 0.f, 0.f, 0.f);
    }

    for (int kb = 0; kb < span; kb += CH) {
        int klen = span - kb; if (klen > CH) klen = CH;

        // ---- async stage (verbatim R8/R13/R17): linear dest == read ----
        for (int r = wave; r < klen; r += NW) {
            const char* g = (const char*)(gbase + (size_t)(kb + r) * H);
            __builtin_amdgcn_global_load_lds(
                (const AS1 void*)(g + lane * 16),
                (AS3 void*)&rows[r][0], 16, 0, 0);
            __builtin_amdgcn_global_load_lds(
                (const AS1 void*)(g + 1024 + lane * 16),
                (AS3 void*)&rows[r][256], 16, 0, 0);
        }

        // ---- per-lane weights (verbatim expression; overlaps DMA) ----
        int nidx = n0 + kb + lane;
        int ci = nidx; if (ci > N - 1) ci = N - 1;
        float cv = cb[ci];
        float wv[FPW];
        #pragma unroll
        for (int f = 0; f < FPW; ++f) {
            float d  = tf[f] - cv;
            float wval = __expf(-0.5f * d * d - m_[f]) * iv[f];
            unsigned q = (unsigned)(nidx - a[f]);
            wv[f] = (q < (unsigned)K[f]) ? wval : 0.0f;
        }
        __syncthreads();                   // DMA drained; rows resident

        // ---- fma from LDS, ascending k; readlane broadcast (verbatim) ----
        for (int k = 0; k < klen; ++k) {
            float wk[FPW];
            #pragma unroll
            for (int f = 0; f < FPW; ++f)
                wk[f] = __uint_as_float(
                    __builtin_amdgcn_readlane(__float_as_uint(wv[f]), k));
            const float4* row = (const float4*)rows[k];
            float4 va = row[lane];
            float4 vb = row[64 + lane];
            #pragma unroll
            for (int f = 0; f < FPW; ++f) {
                acc[f][0].x = fmaf(wk[f], va.x, acc[f][0].x);
                acc[f][0].y = fmaf(wk[f], va.y, acc[f][0].y);
                acc[f][0].z = fmaf(wk[f], va.z, acc[f][0].z);
                acc[f][0].w = fmaf(wk[f], va.w, acc[f][0].w);
                acc[f][1].x = fmaf(wk[f], vb.x, acc[f][1].x);
                acc[f][1].y = fmaf(wk[f], vb.y, acc[f][1].y);
                acc[f][1].z = fmaf(wk[f], vb.z, acc[f][1].z);
                acc[f][1].w = fmaf(wk[f], vb.w, acc[f][1].w);
            }
        }
        __syncthreads();                   // rows safe to overwrite
    }

    // ---- store the wave's 8 frames ----
    float* obase = out + ((size_t)b * T + t0) * (size_t)H;
    #pragma unroll
    for (int f = 0; f < FPW; ++f) {
        float4* o = (float4*)(obase + (size_t)f * H);
        o[lane]      = acc[f][0];
        o[64 + lane] = acc[f][1];
    }
}

extern "C" void kernel_launch(void* const* d_in, const int* in_sizes, int n_in,
                              void* d_out, int out_size, void* d_ws, size_t ws_size,
                              hipStream_t stream) {
    const float* x    = (const float*)d_in[0];  // [B,N,H] f32
    const int*   lens = (const int*)d_in[1];    // [B] int
    const float* dur  = (const float*)d_in[2];  // [B,N] f32

    int B  = in_sizes[1];
    int BN = in_sizes[2];
    int N  = BN / B;
    int H  = in_sizes[0] / BN;
    int T  = out_size / (B * H);

    size_t cB = (size_t)B * N * sizeof(float);
    cB = (cB + 15) & ~(size_t)15;               // align pm to 16B

    float*  c  = (float*)d_ws;
    float4* pm = (float4*)((char*)d_ws + cB);   // B*T float4 (4 MB)

    prep_kernel<<<B * (T >> 8), 256, 0, stream>>>(dur, lens, c, pm, N, T);

    int blocks = (B * T) / FPB;                 // 32 frames per block
    upsample_rl<<<blocks, 256, 0, stream>>>(x, c, pm, (float*)d_out,
                                            B, N, H, T);
}